// Round 2
// baseline (252.328 us; speedup 1.0000x reference)
//
#include <hip/hip_runtime.h>

#define NP   16
#define EDIM 64
#define HH   8
#define BB   2
#define LL   2048
#define SS   2048
#define NQT  32
#define LDP  72            // LDS row stride in bf16 (64 + 8 pad)

typedef __attribute__((ext_vector_type(8))) short bf16x8;
typedef __attribute__((ext_vector_type(4))) float f32x4;

__device__ __forceinline__ float bf2f(unsigned int u) {
    union { unsigned int i; float f; } x; x.i = u << 16; return x.f;
}
__device__ __forceinline__ unsigned short f2bf(float f) {
    union { float ff; unsigned int i; } x; x.ff = f;
    unsigned int r = x.i + 0x7fffu + ((x.i >> 16) & 1u);
    return (unsigned short)(r >> 16);
}
__device__ __forceinline__ unsigned int pk2(float a, float b) {
    return (unsigned int)f2bf(a) | ((unsigned int)f2bf(b) << 16);
}
__device__ __forceinline__ unsigned int tpk2(float a, float b) {   // truncate-pack
    union { float f; unsigned int i; } xa, xb; xa.f = a; xb.f = b;
    return (xa.i >> 16) | (xb.i & 0xffff0000u);
}

// 16 fp32 (global) -> 16 bf16 (LDS), scaled
__device__ __forceinline__ void stage16s(const float* __restrict__ g, unsigned short* l, float sc) {
    const float4* gp = (const float4*)g;
    float4 v0 = gp[0], v1 = gp[1], v2 = gp[2], v3 = gp[3];
    uint4 w0, w1;
    w0.x = pk2(v0.x * sc, v0.y * sc); w0.y = pk2(v0.z * sc, v0.w * sc);
    w0.z = pk2(v1.x * sc, v1.y * sc); w0.w = pk2(v1.z * sc, v1.w * sc);
    w1.x = pk2(v2.x * sc, v2.y * sc); w1.y = pk2(v2.z * sc, v2.w * sc);
    w1.z = pk2(v3.x * sc, v3.y * sc); w1.w = pk2(v3.z * sc, v3.w * sc);
    ((uint4*)l)[0] = w0; ((uint4*)l)[1] = w1;
}

#define INV4PI 0.07957747154594767f

// Grid-barrier state: __device__ globals are zero-initialized at module load
// and are NOT part of the poisoned workspace. Monotonic phase counter makes
// the barrier reusable across graph replays with no reset launch.
__device__ unsigned int g_cnt   = 0;
__device__ unsigned int g_phase = 0;

// ---------------------------------------------------------------------------
// Single fused kernel: 512 blocks x 256 threads, exactly 2 blocks/CU
// (LDS 57.7 KB <= 80 KB, VGPR forced <= 256) -> all 512 blocks co-resident,
// so the software grid barrier between phase 1 and phase 2 cannot deadlock.
//   Phase 1: wave 0 = qev-lite for 64 tokens (r11-proven body),
//            wave 1 = K fp32->bf16 conversion chunk, waves 2-3 idle.
//   Barrier: device-scope atomics + agent fences (cross-XCD L2 writeback /
//            invalidate handled by __threadfence + scoped atomics).
//   Phase 2: attn7 body verbatim (wave-owned-tile MFMA attention) with
//            s_setprio(1) wrapped around the MFMA clusters (T5).
// Removes one kernel-dispatch boundary and keeps Kb/qevb L2-warm.
// ---------------------------------------------------------------------------
__global__ __launch_bounds__(256, 2)
void fused_kernel(const float* __restrict__ qry,     // [B,L,H,E] fp32
                  const float* __restrict__ key,     // [B,S,H,E] fp32
                  const float* __restrict__ values,  // [B,S,H,E] fp32
                  const float* __restrict__ Wang, const float* __restrict__ bang,
                  const float* __restrict__ Wout, const float* __restrict__ bout,
                  unsigned short* __restrict__ qevb, // [B,H,E,S] bf16
                  unsigned short* __restrict__ Kb,   // [B,H,S,E] bf16
                  float* __restrict__ out)           // [B,L,H,E] fp32
{
    __shared__ float sW[NP * EDIM];
    __shared__ float sWo[EDIM * 12];
    __shared__ float sba[NP];
    __shared__ float sbo[EDIM];
    __shared__ unsigned short Qs[64 * LDP];
    __shared__ unsigned short Pq[4][64 * LDP];   // per-wave P[q][s] / O-partial[q][e]
    __shared__ float Lbuf[16 * 64];

    const int tid  = threadIdx.x;
    const int id   = blockIdx.x;
    const int w    = tid >> 6;
    const int lane = tid & 63;

    // ================= phase 1 =================
    // block-wide cooperative weight staging (no per-wave syncs inside bodies)
    ((float4*)sW)[tid & 255] = ((const float4*)Wang)[tid & 255];
    if (tid < 192) ((float4*)sWo)[tid] = ((const float4*)Wout)[tid];
    if (tid < NP) sba[tid] = bang[tid];
    if (tid < 64) sbo[tid] = bout[tid];
    __syncthreads();

    const int chunk = id >> 4;        // s-chunk 0..31
    const int hb1   = id & 15;
    const int h1    = hb1 & 7;
    const int b1    = hb1 >> 3;
    const int s0p   = chunk * 64;

    if (w == 0) {
        // ---------------- qev-lite (one thread per token) ----------------
        const float* vptr = values + ((size_t)(b1 * SS + s0p + lane) * HH + h1) * EDIM;
        float4 vv[16];
#pragma unroll
        for (int c = 0; c < 16; c++) vv[c] = ((const float4*)vptr)[c];

        float ang[NP];
#pragma unroll
        for (int p = 0; p < NP; p++) ang[p] = sba[p];
#pragma unroll
        for (int c = 0; c < 16; c++) {
#pragma unroll
            for (int p = 0; p < NP; p++) {
                float a = ang[p];
                a = fmaf(sW[p * EDIM + c * 4 + 0], vv[c].x, a);
                a = fmaf(sW[p * EDIM + c * 4 + 1], vv[c].y, a);
                a = fmaf(sW[p * EDIM + c * 4 + 2], vv[c].z, a);
                a = fmaf(sW[p * EDIM + c * 4 + 3], vv[c].w, a);
                ang[p] = a;
            }
        }

        float sc[NP], cc[NP];
#pragma unroll
        for (int p = 0; p < NP; p++) {
            float u = ang[p] * INV4PI;
            sc[p] = __builtin_amdgcn_sinf(u);
            cc[p] = __builtin_amdgcn_cosf(u);
        }

        float sr[16], si[16];
#pragma unroll
        for (int i = 0; i < 16; i++) { sr[i] = 0.f; si[i] = 0.f; }
        sr[0] = 1.f;

        auto RY = [&](int wq, float s, float c) {
            const int bit = 8 >> wq;
#pragma unroll
            for (int i = 0; i < 16; i++) {
                if (!(i & bit)) {
                    const int j = i | bit;
                    float a0r = sr[i], a0i = si[i], a1r = sr[j], a1i = si[j];
                    sr[i] = c * a0r - s * a1r;  si[i] = c * a0i - s * a1i;
                    sr[j] = s * a0r + c * a1r;  si[j] = s * a0i + c * a1i;
                }
            }
        };
        auto CRX = [&](int cw, int tw, float s, float c) {
            const int cbit = 8 >> cw, tbit = 8 >> tw;
#pragma unroll
            for (int i = 0; i < 16; i++) {
                if ((i & cbit) && !(i & tbit)) {
                    const int j = i | tbit;
                    float a0r = sr[i], a0i = si[i], a1r = sr[j], a1i = si[j];
                    sr[i] =  c * a0r + s * a1i;  si[i] =  c * a0i - s * a1r;
                    sr[j] =  s * a0i + c * a1r;  si[j] = -s * a0r + c * a1i;
                }
            }
        };

        RY(0, sc[0], cc[0]); RY(1, sc[1], cc[1]); RY(2, sc[2], cc[2]); RY(3, sc[3], cc[3]);
        CRX(3, 0, sc[4], cc[4]); CRX(2, 3, sc[5], cc[5]); CRX(1, 2, sc[6], cc[6]); CRX(0, 1, sc[7], cc[7]);
        RY(0, sc[8], cc[8]); RY(1, sc[9], cc[9]); RY(2, sc[10], cc[10]); RY(3, sc[11], cc[11]);
        CRX(3, 2, sc[12], cc[12]); CRX(0, 3, sc[13], cc[13]); CRX(1, 0, sc[14], cc[14]); CRX(2, 1, sc[15], cc[15]);

        float meas[12];
#pragma unroll
        for (int wq = 0; wq < 4; wq++) {
            const int bit = 8 >> wq;
            float pr = 0.f, pi = 0.f, z = 0.f;
#pragma unroll
            for (int i = 0; i < 16; i++) {
                if (!(i & bit)) {
                    const int j = i | bit;
                    pr += sr[i] * sr[j] + si[i] * si[j];
                    pi += sr[i] * si[j] - si[i] * sr[j];
                    z  += sr[i] * sr[i] + si[i] * si[i] - sr[j] * sr[j] - si[j] * si[j];
                }
            }
            meas[wq] = 2.f * pr; meas[4 + wq] = 2.f * pi; meas[8 + wq] = z;
        }

        unsigned short* ob = qevb + ((size_t)(b1 * HH + h1) * EDIM) * SS + s0p + lane;
#pragma unroll
        for (int eb = 0; eb < 4; eb++) {
            float acc[16];
#pragma unroll
            for (int j = 0; j < 16; j++) acc[j] = sbo[eb * 16 + j];
#pragma unroll
            for (int mm = 0; mm < 12; mm++)
#pragma unroll
                for (int j = 0; j < 16; j++)
                    acc[j] = fmaf(meas[mm], sWo[(eb * 16 + j) * 12 + mm], acc[j]);
#pragma unroll
            for (int j = 0; j < 16; j++)
                ob[(size_t)(eb * 16 + j) * SS] = f2bf(acc[j]);
        }
    } else if (w == 1) {
        // ---------------- K fp32 -> bf16 conversion chunk ----------------
        const float* ks = key + ((size_t)b1 * SS * HH + h1) * EDIM;
        unsigned short* kd = Kb + ((size_t)(b1 * HH + h1) * SS + s0p) * EDIM;
        float4 v[16];
#pragma unroll
        for (int i = 0; i < 16; i++) {
            const int u = i * 64 + lane;
            const int row = u >> 4, ch = u & 15;
            v[i] = *(const float4*)(ks + (size_t)(s0p + row) * HH * EDIM + ch * 4);
        }
#pragma unroll
        for (int i = 0; i < 16; i++) {
            const int u = i * 64 + lane;
            const int row = u >> 4, ch = u & 15;
            uint2 w2; w2.x = pk2(v[i].x, v[i].y); w2.y = pk2(v[i].z, v[i].w);
            *(uint2*)&kd[row * EDIM + ch * 4] = w2;
        }
    }
    // waves 2,3: no phase-1 work

    // ================= grid barrier =================
    __threadfence();          // publish phase-1 stores device-wide (L2 writeback)
    __syncthreads();          // all waves of the block done
    if (tid == 0) {
        const unsigned int ph = __hip_atomic_load(&g_phase, __ATOMIC_ACQUIRE, __HIP_MEMORY_SCOPE_AGENT);
        const unsigned int old = __hip_atomic_fetch_add(&g_cnt, 1u, __ATOMIC_ACQ_REL, __HIP_MEMORY_SCOPE_AGENT);
        if (old == (unsigned int)(gridDim.x - 1)) {
            __hip_atomic_store(&g_cnt, 0u, __ATOMIC_RELAXED, __HIP_MEMORY_SCOPE_AGENT);
            __hip_atomic_fetch_add(&g_phase, 1u, __ATOMIC_RELEASE, __HIP_MEMORY_SCOPE_AGENT);
        } else {
            while (__hip_atomic_load(&g_phase, __ATOMIC_ACQUIRE, __HIP_MEMORY_SCOPE_AGENT) == ph)
                __builtin_amdgcn_s_sleep(8);
        }
    }
    __syncthreads();
    __threadfence();          // invalidate stale cached lines before phase-2 reads

    // ================= phase 2: attention =================
    const int hf2 = id >> 8;                     // 0: qt=0..15, 1: qt=31..16
    const int r   = id & 255;
    const int qt  = hf2 ? (NQT - 1 - (r >> 4)) : (r >> 4);
    const int hb  = r & 15;
    const int h   = hb & 7;
    const int b   = hb >> 3;

    const int ml   = lane & 15;
    const int quad = lane >> 4;
    const int srow = tid >> 2;
    const int sch  = tid & 3;

    const unsigned short* kbase = Kb + (size_t)(b * HH + h) * SS * EDIM;
    const unsigned short* vbase = qevb + (size_t)(b * HH + h) * EDIM * SS;
    unsigned short* Pw = &Pq[w][0];

    const int q0 = qt * 64;

    stage16s(qry + (((size_t)b * LL + q0 + srow) * HH + h) * EDIM + sch * 16,
             &Qs[srow * LDP + sch * 16], 0.125f);
    __syncthreads();

    // Q B-fragments (rows = q), loop-invariant
    bf16x8 bq[4][2];
#pragma unroll
    for (int ntq = 0; ntq < 4; ntq++) {
        bq[ntq][0] = *(const bf16x8*)&Qs[(16 * ntq + ml) * LDP + quad * 8];
        bq[ntq][1] = *(const bf16x8*)&Qs[(16 * ntq + ml) * LDP + quad * 8 + 32];
    }

    f32x4 oaccT[4][4];    // [mte][ntq]: O^T[e][q]
    float lacc[4] = {0.f, 0.f, 0.f, 0.f};
#pragma unroll
    for (int i = 0; i < 4; i++)
#pragma unroll
        for (int j = 0; j < 4; j++) oaccT[i][j] = (f32x4)(0.f);

    int t = w;
    uint4 kc[8];
    if (t <= qt) {
#pragma unroll
        for (int f = 0; f < 8; f++) {
            const int mt = f >> 1, hf = f & 1;
            kc[f] = *(const uint4*)(kbase + (size_t)(t * 64 + 16 * mt + ml) * EDIM + quad * 8 + 32 * hf);
        }
    }

    for (; t <= qt; t += 4) {
        const bool diag = (t == qt);
        const bool more = (t + 4 <= qt);

        // V just-in-time: issued before the S-phase, consumed after it
        uint4 vc[8];
#pragma unroll
        for (int f = 0; f < 8; f++) {
            const int mt = f >> 1, hf = f & 1;
            vc[f] = *(const uint4*)(vbase + (size_t)(16 * mt + ml) * SS + t * 64 + quad * 8 + 32 * hf);
        }
        // K prefetch one tile ahead (issued after V so waiting on V doesn't drain it)
        uint4 kn[8];
        if (more) {
#pragma unroll
            for (int f = 0; f < 8; f++) {
                const int mt = f >> 1, hf = f & 1;
                kn[f] = *(const uint4*)(kbase + (size_t)((t + 4) * 64 + 16 * mt + ml) * EDIM + quad * 8 + 32 * hf);
            }
        }

        // ---- S^T = K*Q^T, exp, pack into Pw[q][s] ----
        __builtin_amdgcn_s_setprio(1);
#pragma unroll
        for (int mts = 0; mts < 4; mts++)
#pragma unroll
            for (int ntq = 0; ntq < 4; ntq++) {
                f32x4 s = __builtin_amdgcn_mfma_f32_16x16x32_bf16(
                    *(const bf16x8*)&kc[2 * mts], bq[ntq][0], (f32x4)(0.f), 0, 0, 0);
                s = __builtin_amdgcn_mfma_f32_16x16x32_bf16(
                    *(const bf16x8*)&kc[2 * mts + 1], bq[ntq][1], s, 0, 0, 0);
                float p0 = __expf(s[0]), p1 = __expf(s[1]), p2 = __expf(s[2]), p3 = __expf(s[3]);
                if (diag) {
                    const int sbase = 16 * mts + 4 * quad, qcol = 16 * ntq + ml;
                    if (sbase + 0 > qcol) p0 = 0.f;
                    if (sbase + 1 > qcol) p1 = 0.f;
                    if (sbase + 2 > qcol) p2 = 0.f;
                    if (sbase + 3 > qcol) p3 = 0.f;
                }
                lacc[ntq] += (p0 + p1) + (p2 + p3);
                uint2 u; u.x = tpk2(p0, p1); u.y = tpk2(p2, p3);
                *(uint2*)&Pw[(16 * ntq + ml) * LDP + 16 * mts + 4 * quad] = u;
            }
        __builtin_amdgcn_s_setprio(0);

        // ---- O^T += V^T * P^T (wave-private LDS round trip, no barrier) ----
        __builtin_amdgcn_s_setprio(1);
#pragma unroll
        for (int ntq = 0; ntq < 4; ntq++) {
            bf16x8 pb0 = *(const bf16x8*)&Pw[(16 * ntq + ml) * LDP + quad * 8];
            bf16x8 pb1 = *(const bf16x8*)&Pw[(16 * ntq + ml) * LDP + quad * 8 + 32];
#pragma unroll
            for (int mte = 0; mte < 4; mte++) {
                oaccT[mte][ntq] = __builtin_amdgcn_mfma_f32_16x16x32_bf16(
                    *(const bf16x8*)&vc[2 * mte], pb0, oaccT[mte][ntq], 0, 0, 0);
                oaccT[mte][ntq] = __builtin_amdgcn_mfma_f32_16x16x32_bf16(
                    *(const bf16x8*)&vc[2 * mte + 1], pb1, oaccT[mte][ntq], 0, 0, 0);
            }
        }
        __builtin_amdgcn_s_setprio(0);

        if (more) {
#pragma unroll
            for (int f = 0; f < 8; f++) kc[f] = kn[f];
        }
    }

    // ---- write partials: O^T (bf16, rows=[q][e]) + l ----
#pragma unroll
    for (int mte = 0; mte < 4; mte++)
#pragma unroll
        for (int ntq = 0; ntq < 4; ntq++) {
            uint2 u;
            u.x = pk2(oaccT[mte][ntq][0], oaccT[mte][ntq][1]);
            u.y = pk2(oaccT[mte][ntq][2], oaccT[mte][ntq][3]);
            *(uint2*)&Pw[(16 * ntq + ml) * LDP + 16 * mte + 4 * quad] = u;
        }
#pragma unroll
    for (int ntq = 0; ntq < 4; ntq++)
        Lbuf[(w * 4 + quad) * 64 + 16 * ntq + ml] = lacc[ntq];

    __syncthreads();

    // ---- reduce 4 partials, normalize, store fp32 float4 ----
    {
        const int q = tid >> 2, c = tid & 3;
        float lsum = 0.f;
#pragma unroll
        for (int i = 0; i < 16; i++) lsum += Lbuf[i * 64 + q];
        const float inv = 1.f / lsum;
        float* orow = out + (((size_t)b * LL + q0 + q) * HH + h) * EDIM;
#pragma unroll
        for (int c4 = 0; c4 < 4; c4++) {
            const int e0 = c * 16 + c4 * 4;
            float a0 = 0.f, a1 = 0.f, a2 = 0.f, a3 = 0.f;
#pragma unroll
            for (int wv = 0; wv < 4; wv++) {
                uint2 u = *(const uint2*)&Pq[wv][q * LDP + e0];
                a0 += bf2f(u.x & 0xffffu); a1 += bf2f(u.x >> 16);
                a2 += bf2f(u.y & 0xffffu); a3 += bf2f(u.y >> 16);
            }
            float4 r4; r4.x = a0 * inv; r4.y = a1 * inv; r4.z = a2 * inv; r4.w = a3 * inv;
            *(float4*)&orow[e0] = r4;
        }
    }
}

extern "C" void kernel_launch(void* const* d_in, const int* in_sizes, int n_in,
                              void* d_out, int out_size, void* d_ws, size_t ws_size,
                              hipStream_t stream)
{
    const float* qry  = (const float*)d_in[0];
    const float* key  = (const float*)d_in[1];
    const float* val  = (const float*)d_in[2];
    const float* Wang = (const float*)d_in[3];
    const float* bang = (const float*)d_in[4];
    const float* Wout = (const float*)d_in[5];
    const float* bout = (const float*)d_in[6];
    float* out = (float*)d_out;

    const size_t seg = (size_t)BB * HH * EDIM * SS * 2;   // 4 MB per bf16 tensor
    unsigned short* qevb = (unsigned short*)d_ws;
    unsigned short* Kb   = (unsigned short*)((char*)d_ws + seg);

    (void)in_sizes; (void)n_in; (void)out_size; (void)ws_size;

    fused_kernel<<<dim3(512, 1, 1), 256, 0, stream>>>(
        qry, key, val, Wang, bang, Wout, bout, qevb, Kb, out);
}

// Round 3
// 112.627 us; speedup vs baseline: 2.2404x; 2.2404x over previous
//
#include <hip/hip_runtime.h>

#define NP   16
#define EDIM 64
#define HH   8
#define BB   2
#define LL   2048
#define SS   2048
#define NQT  32
#define LDP  72            // LDS row stride in bf16 (64 + 8 pad)

typedef __attribute__((ext_vector_type(8))) short bf16x8;
typedef __attribute__((ext_vector_type(4))) float f32x4;

__device__ __forceinline__ float bf2f(unsigned int u) {
    union { unsigned int i; float f; } x; x.i = u << 16; return x.f;
}
__device__ __forceinline__ unsigned short f2bf(float f) {
    union { float ff; unsigned int i; } x; x.ff = f;
    unsigned int r = x.i + 0x7fffu + ((x.i >> 16) & 1u);
    return (unsigned short)(r >> 16);
}
__device__ __forceinline__ unsigned int pk2(float a, float b) {
    return (unsigned int)f2bf(a) | ((unsigned int)f2bf(b) << 16);
}
__device__ __forceinline__ unsigned int tpk2(float a, float b) {   // truncate-pack
    union { float f; unsigned int i; } xa, xb; xa.f = a; xb.f = b;
    return (xa.i >> 16) | (xb.i & 0xffff0000u);
}

// 16 fp32 (global) -> 16 bf16 (LDS), scaled
__device__ __forceinline__ void stage16s(const float* __restrict__ g, unsigned short* l, float sc) {
    const float4* gp = (const float4*)g;
    float4 v0 = gp[0], v1 = gp[1], v2 = gp[2], v3 = gp[3];
    uint4 w0, w1;
    w0.x = pk2(v0.x * sc, v0.y * sc); w0.y = pk2(v0.z * sc, v0.w * sc);
    w0.z = pk2(v1.x * sc, v1.y * sc); w0.w = pk2(v1.z * sc, v1.w * sc);
    w1.x = pk2(v2.x * sc, v2.y * sc); w1.y = pk2(v2.z * sc, v2.w * sc);
    w1.z = pk2(v3.x * sc, v3.y * sc); w1.w = pk2(v3.z * sc, v3.w * sc);
    ((uint4*)l)[0] = w0; ((uint4*)l)[1] = w1;
}

#define INV4PI 0.07957747154594767f

// ---------------------------------------------------------------------------
// Kernel 1: qev + K-conversion, merged into 256-thread blocks.
// Grid (16, H, B); slot = bx*4 + wave:  slot<32 -> qev chunk, else K-conv.
// Bodies are byte-identical to the r11-proven 64-thread versions (lane
// replaces tid). bx<8 blocks stage weights once for 4 qev waves (4x less
// weight re-staging); bx>=8 blocks skip staging entirely.
// ---------------------------------------------------------------------------
__global__ __launch_bounds__(256)
void qev7_kernel(const float* __restrict__ values,  // [B,S,H,E]
                 const float* __restrict__ key,     // [B,S,H,E]
                 const float* __restrict__ Wang, const float* __restrict__ bang,
                 const float* __restrict__ Wout, const float* __restrict__ bout,
                 unsigned short* __restrict__ qevb, // [B,H,E,S]
                 unsigned short* __restrict__ Kb)   // [B,H,S,E]
{
    __shared__ float sW[NP * EDIM];
    __shared__ float sWo[EDIM * 12];
    __shared__ float sba[NP];
    __shared__ float sbo[EDIM];

    const int tid  = threadIdx.x;
    const int bx   = blockIdx.x;
    const int h    = blockIdx.y;
    const int b    = blockIdx.z;
    const int w    = tid >> 6;
    const int lane = tid & 63;
    const int slot = bx * 4 + w;

    if (bx >= 8) {
        // ---------------- K-conversion (4 chunks per block) ----------------
        const int s0 = (slot - 32) * 64;
        const float* ks = key + ((size_t)b * SS * HH + h) * EDIM;
        unsigned short* kd = Kb + ((size_t)(b * HH + h) * SS + s0) * EDIM;
        float4 v[16];
#pragma unroll
        for (int i = 0; i < 16; i++) {
            const int u = i * 64 + lane;
            const int row = u >> 4, ch = u & 15;
            v[i] = *(const float4*)(ks + (size_t)(s0 + row) * HH * EDIM + ch * 4);
        }
#pragma unroll
        for (int i = 0; i < 16; i++) {
            const int u = i * 64 + lane;
            const int row = u >> 4, ch = u & 15;
            uint2 w2; w2.x = pk2(v[i].x, v[i].y); w2.y = pk2(v[i].z, v[i].w);
            *(uint2*)&kd[row * EDIM + ch * 4] = w2;
        }
        return;
    }

    // ---------------- qev-lite (4 chunks per block) ----------------
    ((float4*)sW)[tid] = ((const float4*)Wang)[tid];
    if (tid < 192) ((float4*)sWo)[tid] = ((const float4*)Wout)[tid];
    if (tid < NP) sba[tid] = bang[tid];
    if (tid < 64) sbo[tid] = bout[tid];
    __syncthreads();

    const int s0 = slot * 64;

    // hoisted value loads (16 independent float4s)
    const float* vptr = values + ((size_t)(b * SS + s0 + lane) * HH + h) * EDIM;
    float4 vv[16];
#pragma unroll
    for (int c = 0; c < 16; c++) vv[c] = ((const float4*)vptr)[c];

    float ang[NP];
#pragma unroll
    for (int p = 0; p < NP; p++) ang[p] = sba[p];
#pragma unroll
    for (int c = 0; c < 16; c++) {
#pragma unroll
        for (int p = 0; p < NP; p++) {
            float a = ang[p];
            a = fmaf(sW[p * EDIM + c * 4 + 0], vv[c].x, a);
            a = fmaf(sW[p * EDIM + c * 4 + 1], vv[c].y, a);
            a = fmaf(sW[p * EDIM + c * 4 + 2], vv[c].z, a);
            a = fmaf(sW[p * EDIM + c * 4 + 3], vv[c].w, a);
            ang[p] = a;
        }
    }

    float sc[NP], cc[NP];
#pragma unroll
    for (int p = 0; p < NP; p++) {
        float u = ang[p] * INV4PI;
        sc[p] = __builtin_amdgcn_sinf(u);
        cc[p] = __builtin_amdgcn_cosf(u);
    }

    float sr[16], si[16];
#pragma unroll
    for (int i = 0; i < 16; i++) { sr[i] = 0.f; si[i] = 0.f; }
    sr[0] = 1.f;

    auto RY = [&](int wq, float s, float c) {
        const int bit = 8 >> wq;
#pragma unroll
        for (int i = 0; i < 16; i++) {
            if (!(i & bit)) {
                const int j = i | bit;
                float a0r = sr[i], a0i = si[i], a1r = sr[j], a1i = si[j];
                sr[i] = c * a0r - s * a1r;  si[i] = c * a0i - s * a1i;
                sr[j] = s * a0r + c * a1r;  si[j] = s * a0i + c * a1i;
            }
        }
    };
    auto CRX = [&](int cw, int tw, float s, float c) {
        const int cbit = 8 >> cw, tbit = 8 >> tw;
#pragma unroll
        for (int i = 0; i < 16; i++) {
            if ((i & cbit) && !(i & tbit)) {
                const int j = i | tbit;
                float a0r = sr[i], a0i = si[i], a1r = sr[j], a1i = si[j];
                sr[i] =  c * a0r + s * a1i;  si[i] =  c * a0i - s * a1r;
                sr[j] =  s * a0i + c * a1r;  si[j] = -s * a0r + c * a1i;
            }
        }
    };

    RY(0, sc[0], cc[0]); RY(1, sc[1], cc[1]); RY(2, sc[2], cc[2]); RY(3, sc[3], cc[3]);
    CRX(3, 0, sc[4], cc[4]); CRX(2, 3, sc[5], cc[5]); CRX(1, 2, sc[6], cc[6]); CRX(0, 1, sc[7], cc[7]);
    RY(0, sc[8], cc[8]); RY(1, sc[9], cc[9]); RY(2, sc[10], cc[10]); RY(3, sc[11], cc[11]);
    CRX(3, 2, sc[12], cc[12]); CRX(0, 3, sc[13], cc[13]); CRX(1, 0, sc[14], cc[14]); CRX(2, 1, sc[15], cc[15]);

    float meas[12];
#pragma unroll
    for (int wq = 0; wq < 4; wq++) {
        const int bit = 8 >> wq;
        float pr = 0.f, pi = 0.f, z = 0.f;
#pragma unroll
        for (int i = 0; i < 16; i++) {
            if (!(i & bit)) {
                const int j = i | bit;
                pr += sr[i] * sr[j] + si[i] * si[j];
                pi += sr[i] * si[j] - si[i] * sr[j];
                z  += sr[i] * sr[i] + si[i] * si[i] - sr[j] * sr[j] - si[j] * si[j];
            }
        }
        meas[wq] = 2.f * pr; meas[4 + wq] = 2.f * pi; meas[8 + wq] = z;
    }

    unsigned short* ob = qevb + ((size_t)(b * HH + h) * EDIM) * SS + s0 + lane;
#pragma unroll
    for (int eb = 0; eb < 4; eb++) {
        float acc[16];
#pragma unroll
        for (int j = 0; j < 16; j++) acc[j] = sbo[eb * 16 + j];
#pragma unroll
        for (int mm = 0; mm < 12; mm++)
#pragma unroll
            for (int j = 0; j < 16; j++)
                acc[j] = fmaf(meas[mm], sWo[(eb * 16 + j) * 12 + mm], acc[j]);
#pragma unroll
        for (int j = 0; j < 16; j++)
            ob[(size_t)(eb * 16 + j) * SS] = f2bf(acc[j]);
    }
}

// ---------------------------------------------------------------------------
// Kernel 2: wave-owned-tile MFMA attention (r1-proven attn7 structure,
// 512 one-tile blocks, 2 blocks/CU) + s_setprio around the MFMA clusters
// (T5: independent blocks at different loop phases -> scheduler has
// something to arbitrate; attn-regime measured +4-7%).
// ---------------------------------------------------------------------------
__global__ __launch_bounds__(256, 2)
void attn8_kernel(const float* __restrict__ qry,            // [B,L,H,E] fp32
                  const unsigned short* __restrict__ Kb,    // [B,H,S,E] bf16
                  const unsigned short* __restrict__ Vb,    // [B,H,E,S] bf16
                  float* __restrict__ out)                  // [B,L,H,E] fp32
{
    __shared__ unsigned short Qs[64 * LDP];
    __shared__ unsigned short Pq[4][64 * LDP];   // per-wave P[q][s] / O-partial[q][e]
    __shared__ float Lbuf[16 * 64];

    const int tid  = threadIdx.x;
    const int id   = blockIdx.x;
    const int hf2  = id >> 8;                    // 0: qt=0..15, 1: qt=31..16
    const int r    = id & 255;
    const int qt   = hf2 ? (NQT - 1 - (r >> 4)) : (r >> 4);
    const int hb   = r & 15;
    const int h    = hb & 7;
    const int b    = hb >> 3;

    const int w    = tid >> 6;
    const int lane = tid & 63;
    const int ml   = lane & 15;
    const int quad = lane >> 4;
    const int srow = tid >> 2;
    const int sch  = tid & 3;

    const unsigned short* kbase = Kb + (size_t)(b * HH + h) * SS * EDIM;
    const unsigned short* vbase = Vb + (size_t)(b * HH + h) * EDIM * SS;
    unsigned short* Pw = &Pq[w][0];

    const int q0 = qt * 64;

    stage16s(qry + (((size_t)b * LL + q0 + srow) * HH + h) * EDIM + sch * 16,
             &Qs[srow * LDP + sch * 16], 0.125f);
    __syncthreads();

    // Q B-fragments (rows = q), loop-invariant
    bf16x8 bq[4][2];
#pragma unroll
    for (int ntq = 0; ntq < 4; ntq++) {
        bq[ntq][0] = *(const bf16x8*)&Qs[(16 * ntq + ml) * LDP + quad * 8];
        bq[ntq][1] = *(const bf16x8*)&Qs[(16 * ntq + ml) * LDP + quad * 8 + 32];
    }

    f32x4 oaccT[4][4];    // [mte][ntq]: O^T[e][q]
    float lacc[4] = {0.f, 0.f, 0.f, 0.f};
#pragma unroll
    for (int i = 0; i < 4; i++)
#pragma unroll
        for (int j = 0; j < 4; j++) oaccT[i][j] = (f32x4)(0.f);

    int t = w;
    uint4 kc[8];
    if (t <= qt) {
#pragma unroll
        for (int f = 0; f < 8; f++) {
            const int mt = f >> 1, hf = f & 1;
            kc[f] = *(const uint4*)(kbase + (size_t)(t * 64 + 16 * mt + ml) * EDIM + quad * 8 + 32 * hf);
        }
    }

    for (; t <= qt; t += 4) {
        const bool diag = (t == qt);
        const bool more = (t + 4 <= qt);

        // V just-in-time: issued before the S-phase, consumed after it
        uint4 vc[8];
#pragma unroll
        for (int f = 0; f < 8; f++) {
            const int mt = f >> 1, hf = f & 1;
            vc[f] = *(const uint4*)(vbase + (size_t)(16 * mt + ml) * SS + t * 64 + quad * 8 + 32 * hf);
        }
        // K prefetch one tile ahead (issued after V so waiting on V doesn't drain it)
        uint4 kn[8];
        if (more) {
#pragma unroll
            for (int f = 0; f < 8; f++) {
                const int mt = f >> 1, hf = f & 1;
                kn[f] = *(const uint4*)(kbase + (size_t)((t + 4) * 64 + 16 * mt + ml) * EDIM + quad * 8 + 32 * hf);
            }
        }

        // ---- S^T = K*Q^T, exp, pack into Pw[q][s] ----
        __builtin_amdgcn_s_setprio(1);
#pragma unroll
        for (int mts = 0; mts < 4; mts++)
#pragma unroll
            for (int ntq = 0; ntq < 4; ntq++) {
                f32x4 s = __builtin_amdgcn_mfma_f32_16x16x32_bf16(
                    *(const bf16x8*)&kc[2 * mts], bq[ntq][0], (f32x4)(0.f), 0, 0, 0);
                s = __builtin_amdgcn_mfma_f32_16x16x32_bf16(
                    *(const bf16x8*)&kc[2 * mts + 1], bq[ntq][1], s, 0, 0, 0);
                float p0 = __expf(s[0]), p1 = __expf(s[1]), p2 = __expf(s[2]), p3 = __expf(s[3]);
                if (diag) {
                    const int sbase = 16 * mts + 4 * quad, qcol = 16 * ntq + ml;
                    if (sbase + 0 > qcol) p0 = 0.f;
                    if (sbase + 1 > qcol) p1 = 0.f;
                    if (sbase + 2 > qcol) p2 = 0.f;
                    if (sbase + 3 > qcol) p3 = 0.f;
                }
                lacc[ntq] += (p0 + p1) + (p2 + p3);
                uint2 u; u.x = tpk2(p0, p1); u.y = tpk2(p2, p3);
                *(uint2*)&Pw[(16 * ntq + ml) * LDP + 16 * mts + 4 * quad] = u;
            }
        __builtin_amdgcn_s_setprio(0);

        // ---- O^T += V^T * P^T (wave-private LDS round trip, no barrier) ----
        __builtin_amdgcn_s_setprio(1);
#pragma unroll
        for (int ntq = 0; ntq < 4; ntq++) {
            bf16x8 pb0 = *(const bf16x8*)&Pw[(16 * ntq + ml) * LDP + quad * 8];
            bf16x8 pb1 = *(const bf16x8*)&Pw[(16 * ntq + ml) * LDP + quad * 8 + 32];
#pragma unroll
            for (int mte = 0; mte < 4; mte++) {
                oaccT[mte][ntq] = __builtin_amdgcn_mfma_f32_16x16x32_bf16(
                    *(const bf16x8*)&vc[2 * mte], pb0, oaccT[mte][ntq], 0, 0, 0);
                oaccT[mte][ntq] = __builtin_amdgcn_mfma_f32_16x16x32_bf16(
                    *(const bf16x8*)&vc[2 * mte + 1], pb1, oaccT[mte][ntq], 0, 0, 0);
            }
        }
        __builtin_amdgcn_s_setprio(0);

        if (more) {
#pragma unroll
            for (int f = 0; f < 8; f++) kc[f] = kn[f];
        }
    }

    // ---- write partials: O^T (bf16, rows=[q][e]) + l ----
#pragma unroll
    for (int mte = 0; mte < 4; mte++)
#pragma unroll
        for (int ntq = 0; ntq < 4; ntq++) {
            uint2 u;
            u.x = pk2(oaccT[mte][ntq][0], oaccT[mte][ntq][1]);
            u.y = pk2(oaccT[mte][ntq][2], oaccT[mte][ntq][3]);
            *(uint2*)&Pw[(16 * ntq + ml) * LDP + 16 * mte + 4 * quad] = u;
        }
#pragma unroll
    for (int ntq = 0; ntq < 4; ntq++)
        Lbuf[(w * 4 + quad) * 64 + 16 * ntq + ml] = lacc[ntq];

    __syncthreads();

    // ---- reduce 4 partials, normalize, store fp32 float4 ----
    {
        const int q = tid >> 2, c = tid & 3;
        float lsum = 0.f;
#pragma unroll
        for (int i = 0; i < 16; i++) lsum += Lbuf[i * 64 + q];
        const float inv = 1.f / lsum;
        float* orow = out + (((size_t)b * LL + q0 + q) * HH + h) * EDIM;
#pragma unroll
        for (int c4 = 0; c4 < 4; c4++) {
            const int e0 = c * 16 + c4 * 4;
            float a0 = 0.f, a1 = 0.f, a2 = 0.f, a3 = 0.f;
#pragma unroll
            for (int wv = 0; wv < 4; wv++) {
                uint2 u = *(const uint2*)&Pq[wv][q * LDP + e0];
                a0 += bf2f(u.x & 0xffffu); a1 += bf2f(u.x >> 16);
                a2 += bf2f(u.y & 0xffffu); a3 += bf2f(u.y >> 16);
            }
            float4 r4; r4.x = a0 * inv; r4.y = a1 * inv; r4.z = a2 * inv; r4.w = a3 * inv;
            *(float4*)&orow[e0] = r4;
        }
    }
}

extern "C" void kernel_launch(void* const* d_in, const int* in_sizes, int n_in,
                              void* d_out, int out_size, void* d_ws, size_t ws_size,
                              hipStream_t stream)
{
    const float* qry  = (const float*)d_in[0];
    const float* key  = (const float*)d_in[1];
    const float* val  = (const float*)d_in[2];
    const float* Wang = (const float*)d_in[3];
    const float* bang = (const float*)d_in[4];
    const float* Wout = (const float*)d_in[5];
    const float* bout = (const float*)d_in[6];
    float* out = (float*)d_out;

    const size_t seg = (size_t)BB * HH * EDIM * SS * 2;   // 4 MB per bf16 tensor
    unsigned short* qevb = (unsigned short*)d_ws;
    unsigned short* Kb   = (unsigned short*)((char*)d_ws + seg);

    (void)in_sizes; (void)n_in; (void)out_size; (void)ws_size;

    qev7_kernel<<<dim3(16, HH, BB), 256, 0, stream>>>(val, key, Wang, bang, Wout, bout, qevb, Kb);
    attn8_kernel<<<dim3(512, 1, 1), 256, 0, stream>>>(qry, Kb, qevb, out);
}